// Round 8
// baseline (51.722 us; speedup 1.0000x reference)
//
#include <hip/hip_runtime.h>

// Problem constants
#define BATCH 512
#define INFEAT 4096
#define LOUT 1023   // code_length - 1
#define NCLS 1000
#define NPAD 1024
#define SPLITK 8
#define KSLICE 512  // K extent per block (INFEAT / SPLITK)
#define NCHUNK 16   // KSLICE / 32

typedef __bf16 bf16x8 __attribute__((ext_vector_type(8)));
typedef float f32x4 __attribute__((ext_vector_type(4)));

__device__ __forceinline__ unsigned short f2bf(float a) {
    unsigned u = __builtin_bit_cast(unsigned, a);
    return (unsigned short)((u + 0x7fffu + ((u >> 16) & 1u)) >> 16);
}
__device__ __forceinline__ float bf2f(unsigned short u) {
    return __builtin_bit_cast(float, ((unsigned)u) << 16);
}
// pack 8 f32 -> 8 bf16 (v_cvt_pk_bf16_f32 pairs)
__device__ __forceinline__ bf16x8 pack8(float4 a, float4 b) {
    union { __bf16 h[8]; bf16x8 v; } r;
    r.h[0] = (__bf16)a.x; r.h[1] = (__bf16)a.y;
    r.h[2] = (__bf16)a.z; r.h[3] = (__bf16)a.w;
    r.h[4] = (__bf16)b.x; r.h[5] = (__bf16)b.y;
    r.h[6] = (__bf16)b.z; r.h[7] = (__bf16)b.w;
    return r.v;
}

// ---------------- GEMM: partial[s] = bf16(x) @ bf16(W)^T (split-K) ----------
// BM=128, BN=128, K=512/block, SK=8 -> 256 blocks x 512 thr = 1 block/CU.
// NO K-loop barriers: the whole W-tile (128x512 bf16 = 128 KB) is staged into
// LDS ONCE (f32->bf16, XOR-swizzled granules), one __syncthreads, then each
// of the 8 waves (2M x 4N) independently streams its A fragments from global
// (L2-resident x-slice) into a 3-deep statically-rotated register pipeline:
// cvt -> 8 MFMA per 32-k chunk. Waves drift freely; no lockstep, no ds_write
// in the loop. A-loads: 64 lanes = 16 rows x 128 B contiguous (full lines).
// Chunked XCD swizzle: each XCD owns one sp-slice (W-slice 2 MB, L2-resident).
__global__ __launch_bounds__(512, 1) void k_gemm(
    const float* __restrict__ x, const float* __restrict__ W,
    unsigned short* __restrict__ partial) {
    __shared__ unsigned char lB[128 * 1024];  // 128 rows x 1024 B (512 bf16)
    const int bid = blockIdx.x;
    const int work = (bid & 7) * 32 + (bid >> 3);   // chunked XCD swizzle
    const int bn = work & 7, bm = (work >> 3) & 3, sp = work >> 5;
    const int tid = threadIdx.x;
    const int wave = tid >> 6, lane = tid & 63;
    const int lrow = lane & 15, lgrp = lane >> 4;
    const int wr = wave >> 2, wc = wave & 3;        // 2 x 4 wave grid
    const int arow0 = bm * 128, brow0 = bn * 128;
    const size_t c0 = (size_t)sp * KSLICE;

    // ---- one-time B stage: W f32 -> bf16, swizzled (granule g at slot
    // g^(row&7); 16B granules, row stride 1024B) ----
    {
        const int r = tid >> 2, s = tid & 3;        // r 0..127, s 0..3
        const int wrow = brow0 + r;
        const float* src = W + (size_t)wrow * INFEAT + c0 + s * 128;
        unsigned char* dst = lB + r * 1024;
#pragma unroll
        for (int i = 0; i < 16; ++i) {              // 16 granules of 8 bf16
            float4 v0, v1;
            if (wrow < LOUT) {
                v0 = *(const float4*)(src + i * 8);
                v1 = *(const float4*)(src + i * 8 + 4);
            } else {
                v0 = make_float4(0.f, 0.f, 0.f, 0.f);
                v1 = v0;
            }
            *(bf16x8*)(dst + (((s * 16 + i) ^ (r & 7)) * 16)) = pack8(v0, v1);
        }
    }
    __syncthreads();   // the ONLY block-wide sync

    f32x4 acc[4][2] = {};
    float4 A0[4][2], A1[4][2], A2[4][2];

    auto LOADA = [&](int kk, float4 (&S)[4][2]) {
#pragma unroll
        for (int m = 0; m < 4; ++m) {
            const float4* q = (const float4*)(x +
                (size_t)(arow0 + wr * 64 + m * 16 + lrow) * INFEAT +
                c0 + kk * 32 + lgrp * 8);
            S[m][0] = q[0]; S[m][1] = q[1];
        }
    };

#define STEP(KK, SCUR)                                                        \
    {                                                                         \
        bf16x8 a[4], b[2];                                                    \
        _Pragma("unroll")                                                     \
        for (int m = 0; m < 4; ++m) a[m] = pack8(SCUR[m][0], SCUR[m][1]);     \
        _Pragma("unroll")                                                     \
        for (int n = 0; n < 2; ++n)                                           \
            b[n] = *(const bf16x8*)(lB + (wc * 32 + n * 16 + lrow) * 1024 +   \
                                    ((((KK) * 4 + lgrp) ^ (lrow & 7)) * 16)); \
        if ((KK) + 3 < NCHUNK) LOADA((KK) + 3, SCUR);                         \
        _Pragma("unroll")                                                     \
        for (int m = 0; m < 4; ++m)                                           \
            _Pragma("unroll")                                                 \
            for (int n = 0; n < 2; ++n)                                       \
                acc[m][n] = __builtin_amdgcn_mfma_f32_16x16x32_bf16(          \
                    a[m], b[n], acc[m][n], 0, 0, 0);                          \
    }

    LOADA(0, A0); LOADA(1, A1); LOADA(2, A2);
    STEP(0, A0)  STEP(1, A1)  STEP(2, A2)
    STEP(3, A0)  STEP(4, A1)  STEP(5, A2)
    STEP(6, A0)  STEP(7, A1)  STEP(8, A2)
    STEP(9, A0)  STEP(10, A1) STEP(11, A2)
    STEP(12, A0) STEP(13, A1) STEP(14, A2)
    STEP(15, A0)
#undef STEP

    // ---- epilogue: bf16 partials ----
    unsigned short* P = partial + (size_t)sp * (BATCH * NPAD);
#pragma unroll
    for (int m = 0; m < 4; ++m)
#pragma unroll
        for (int n = 0; n < 2; ++n)
#pragma unroll
            for (int reg = 0; reg < 4; ++reg) {
                int r = arow0 + wr * 64 + m * 16 + lgrp * 4 + reg;
                int c = brow0 + wc * 32 + n * 16 + lrow;
                P[(size_t)r * NPAD + c] = f2bf(acc[m][n][reg]);
            }
}

// ---------------- fused: split-K reduce + bias + tanh + FWHT + inv + norm ----
// One block per batch row. dot[c] = sum_j h[j]*H[c][j+1] = FWHT(g)[c] with
// g[0]=0, g[k]=h[k-1]  (Sylvester H symmetric; H[c][0]*g[0]=0 drops out).
__global__ __launch_bounds__(256) void k_fused(const unsigned short* __restrict__ partial,
                                               const float* __restrict__ bias,
                                               const float* __restrict__ epsp,
                                               const float* __restrict__ powp,
                                               float* __restrict__ out) {
    __shared__ float g[1024];
    __shared__ float wsum[4];
    const int r = blockIdx.x, t = threadIdx.x;
    const int n0 = t * 4;

    f32x4 v = {0.0f, 0.0f, 0.0f, 0.0f};
#pragma unroll
    for (int s = 0; s < SPLITK; ++s) {
        ushort4 p = *(const ushort4*)(partial + ((size_t)s * BATCH + r) * NPAD + n0);
        v[0] += bf2f(p.x); v[1] += bf2f(p.y); v[2] += bf2f(p.z); v[3] += bf2f(p.w);
    }
    float bb[4];
    if (t < 255) {
        float4 b4 = *(const float4*)(bias + n0);
        bb[0] = b4.x; bb[1] = b4.y; bb[2] = b4.z; bb[3] = b4.w;
    } else {
        bb[0] = bias[1020]; bb[1] = bias[1021]; bb[2] = bias[1022]; bb[3] = 0.0f;
    }
    if (t == 0) g[0] = 0.0f;
#pragma unroll
    for (int j = 0; j < 4; ++j) {
        int n = n0 + j;
        if (n < LOUT) g[n + 1] = tanhf(v[j] + bb[j]);
    }
    __syncthreads();

    // FWHT: 10 stages, 512 butterflies/stage, 2 per thread
#pragma unroll 1
    for (int s = 0; s < 10; ++s) {
        int st = 1 << s;
#pragma unroll
        for (int pp = 0; pp < 2; ++pp) {
            int p = t + pp * 256;
            int idx = ((p >> s) << (s + 1)) | (p & (st - 1));
            float a = g[idx], c = g[idx + st];
            g[idx] = a + c;
            g[idx + st] = a - c;
        }
        __syncthreads();
    }

    const float eps = *epsp, pw = *powp;
    float iv[4];
    float ss = 0.0f;
#pragma unroll
    for (int j = 0; j < 4; ++j) {
        int c = n0 + j;
        float d = fmaxf(1023.0f - g[c], eps);
        float q = (pw == 1.0f) ? (1.0f / d) : powf(d, -pw);
        if (c >= NCLS) q = 0.0f;
        iv[j] = q;
        ss += q;
    }
#pragma unroll
    for (int m = 32; m; m >>= 1) ss += __shfl_xor(ss, m, 64);
    if ((t & 63) == 0) wsum[t >> 6] = ss;
    __syncthreads();
    float sc = 1.0f / (wsum[0] + wsum[1] + wsum[2] + wsum[3]);

    if (n0 < NCLS) {  // NCLS = 1000 = 4*250: threads 0..249 store full float4
        float4 o;
        o.x = iv[0] * sc; o.y = iv[1] * sc; o.z = iv[2] * sc; o.w = iv[3] * sc;
        *(float4*)(out + (size_t)r * NCLS + n0) = o;
    }
}

extern "C" void kernel_launch(void* const* d_in, const int* in_sizes, int n_in,
                              void* d_out, int out_size, void* d_ws, size_t ws_size,
                              hipStream_t stream) {
    const float* x = (const float*)d_in[0];       // (512, 4096)
    const float* W = (const float*)d_in[1];       // (1023, 4096)
    const float* b = (const float*)d_in[2];       // (1023,)
    // d_in[3] = labels: NOT needed (Hadamard structure -> FWHT)
    const float* epsp = (const float*)d_in[4];
    const float* powp = (const float*)d_in[5];
    float* out = (float*)d_out;                   // (512, 1000)

    unsigned char* ws = (unsigned char*)d_ws;
    unsigned short* partial = (unsigned short*)ws;  // 8 MB (8 x 512 x 1024 bf16)

    k_gemm<<<256, 512, 0, stream>>>(x, W, partial);
    k_fused<<<512, 256, 0, stream>>>(partial, b, epsp, powp, out);
}

// Round 9
// 27.065 us; speedup vs baseline: 1.9110x; 1.9110x over previous
//
#include <hip/hip_runtime.h>

// Problem constants
#define BATCH 512
#define INFEAT 4096
#define LOUT 1023   // code_length - 1
#define NCLS 1000
#define NPAD 1024
#define SPLITK 8
#define ROWB 144    // LDS row stride: 128B data + 16B pad -> bank-group = (row+j)&7

typedef __bf16 bf16x8 __attribute__((ext_vector_type(8)));
typedef float f32x4 __attribute__((ext_vector_type(4)));

__device__ __forceinline__ unsigned short f2bf(float a) {
    unsigned u = __builtin_bit_cast(unsigned, a);
    return (unsigned short)((u + 0x7fffu + ((u >> 16) & 1u)) >> 16);
}
__device__ __forceinline__ float bf2f(unsigned short u) {
    return __builtin_bit_cast(float, ((unsigned)u) << 16);
}
// pack 8 f32 -> 8 bf16 (v_cvt_pk_bf16_f32 pairs)
__device__ __forceinline__ uint4 pack8(float4 a, float4 b) {
    union { __bf16 h[8]; uint4 u; } r;
    r.h[0] = (__bf16)a.x; r.h[1] = (__bf16)a.y;
    r.h[2] = (__bf16)a.z; r.h[3] = (__bf16)a.w;
    r.h[4] = (__bf16)b.x; r.h[5] = (__bf16)b.y;
    r.h[6] = (__bf16)b.z; r.h[7] = (__bf16)b.w;
    return r.u;
}

// ---------------- GEMM: partial[s] = bf16(x) @ bf16(W)^T (split-K) ----------
// BM=128, BN=128, BK=64, SK=8 -> 256 blocks x 512 thr, 8 waves (2x4).
// LDS rows PADDED to 144B (no XOR swizzle): granule (row,j) lands in bank
// group (row*9+j)%8 = (row+j)&7, so the frag-read lane set (16 rows x 4
// slots) spreads across bank groups like the linear baseline instead of
// 8-deep serializing on slot-only groups (the R0-R8 invariant ~11us/CU
// LDS stall, diagnosed from R8's SQ_LDS_BANK_CONFLICT=1.05M).
// Reg-staged f32->bf16; loads issued 3 steps ahead; per-step sync =
// lgkmcnt(0) + raw s_barrier. Chunked XCD swizzle keeps each XCD's slice
// (3 MB) L2-resident.
__global__ __launch_bounds__(512, 1) void k_gemm(
    const float* __restrict__ x, const float* __restrict__ W,
    unsigned short* __restrict__ partial) {
    __shared__ unsigned char lds[2 * 2 * 128 * ROWB];   // 73728 B
    const int bid = blockIdx.x;
    const int work = (bid & 7) * 32 + (bid >> 3);   // chunked XCD swizzle
    const int bn = work & 7, bm = (work >> 3) & 3, sp = work >> 5;
    const int tid = threadIdx.x;
    const int wave = tid >> 6, lane = tid & 63;
    const int lrow = lane & 15, lgrp = lane >> 4;
    const int wr = wave >> 2, wc = wave & 3;        // 2 x 4 wave grid
    const int arow0 = bm * 128, brow0 = bn * 128, chunk0 = sp * 8;

    // per-thread staging coords (2 granule-pairs each for A and B)
    const int row0 = tid >> 3, jb0 = tid & 7;       // rows 0..63
    const int row1 = 64 + (tid >> 3), jb1 = tid & 7;  // rows 64..127

    f32x4 acc[4][2] = {};
    float4 sAa[4], sAb[4], sBa[4], sBb[4];

    auto LOADR = [&](int t, float4 (&aa)[4], float4 (&bb)[4]) {
        const size_t c0 = (size_t)(chunk0 + t) * 64;
        {
            const float4* q = (const float4*)(x + (size_t)(arow0 + row0) * INFEAT + c0 + jb0 * 8);
            aa[0] = q[0]; aa[1] = q[1];
        }
        {
            const float4* q = (const float4*)(x + (size_t)(arow0 + row1) * INFEAT + c0 + jb1 * 8);
            aa[2] = q[0]; aa[3] = q[1];
        }
        {
            int wrow = brow0 + row0;
            if (wrow < LOUT) {
                const float4* q = (const float4*)(W + (size_t)wrow * INFEAT + c0 + jb0 * 8);
                bb[0] = q[0]; bb[1] = q[1];
            } else {
                bb[0] = make_float4(0.f, 0.f, 0.f, 0.f);
                bb[1] = make_float4(0.f, 0.f, 0.f, 0.f);
            }
        }
        {
            int wrow = brow0 + row1;
            if (wrow < LOUT) {
                const float4* q = (const float4*)(W + (size_t)wrow * INFEAT + c0 + jb1 * 8);
                bb[2] = q[0]; bb[3] = q[1];
            } else {
                bb[2] = make_float4(0.f, 0.f, 0.f, 0.f);
                bb[3] = make_float4(0.f, 0.f, 0.f, 0.f);
            }
        }
    };

    auto WRITE = [&](int bsel, float4 (&aa)[4], float4 (&bb)[4]) {
        unsigned char* lA = lds + bsel * (2 * 128 * ROWB);
        unsigned char* lB = lA + 128 * ROWB;
        *(uint4*)(lA + row0 * ROWB + jb0 * 16) = pack8(aa[0], aa[1]);
        *(uint4*)(lA + row1 * ROWB + jb1 * 16) = pack8(aa[2], aa[3]);
        *(uint4*)(lB + row0 * ROWB + jb0 * 16) = pack8(bb[0], bb[1]);
        *(uint4*)(lB + row1 * ROWB + jb1 * 16) = pack8(bb[2], bb[3]);
    };

    // one K-step: frag reads of buf cur, stage next buf, MFMA cluster, sync
    auto STEP_BODY = [&](int bsel, float4 (&aa)[4], float4 (&bb)[4],
                         bool do_write, bool do_load, int tload) {
        const unsigned char* lA = lds + bsel * (2 * 128 * ROWB);
        const unsigned char* lB = lA + 128 * ROWB;
        bf16x8 fa[2][4], fb[2][2];
#pragma unroll
        for (int ks = 0; ks < 2; ++ks) {
            int go = (ks * 4 + lgrp) * 16;
#pragma unroll
            for (int m = 0; m < 4; ++m)
                fa[ks][m] = *(const bf16x8*)(lA + (wr * 64 + m * 16 + lrow) * ROWB + go);
#pragma unroll
            for (int n = 0; n < 2; ++n)
                fb[ks][n] = *(const bf16x8*)(lB + (wc * 32 + n * 16 + lrow) * ROWB + go);
        }
        if (do_write) WRITE(bsel ^ 1, aa, bb);
        if (do_load) LOADR(tload, aa, bb);
        __builtin_amdgcn_s_setprio(1);
#pragma unroll
        for (int ks = 0; ks < 2; ++ks)
#pragma unroll
            for (int m = 0; m < 4; ++m)
#pragma unroll
                for (int n = 0; n < 2; ++n)
                    acc[m][n] = __builtin_amdgcn_mfma_f32_16x16x32_bf16(
                        fa[ks][m], fb[ks][n], acc[m][n], 0, 0, 0);
        __builtin_amdgcn_s_setprio(0);
        asm volatile("s_waitcnt lgkmcnt(0)" ::: "memory");
        __builtin_amdgcn_s_barrier();
    };

    // --- prologue ---
    LOADR(0, sAa, sAb);
    LOADR(1, sBa, sBb);
    WRITE(0, sAa, sAb);                 // compiler waits set A's vmcnt
    LOADR(2, sAa, sAb);                 // reissue into set A
    asm volatile("s_waitcnt lgkmcnt(0)" ::: "memory");
    __builtin_amdgcn_s_barrier();       // buf0 ready

    // --- 8 K-steps; set usage: B,A,B,A,B,A,B,- ; write buf t^1 <- chunk t+1 ---
    STEP_BODY(0, sBa, sBb, true, true, 3);
    STEP_BODY(1, sAa, sAb, true, true, 4);
    STEP_BODY(0, sBa, sBb, true, true, 5);
    STEP_BODY(1, sAa, sAb, true, true, 6);
    STEP_BODY(0, sBa, sBb, true, true, 7);
    STEP_BODY(1, sAa, sAb, true, false, 0);
    STEP_BODY(0, sBa, sBb, true, false, 0);
    STEP_BODY(1, sAa, sAb, false, false, 0);

    // --- epilogue: bf16 partials ---
    unsigned short* P = partial + (size_t)sp * (BATCH * NPAD);
#pragma unroll
    for (int m = 0; m < 4; ++m)
#pragma unroll
        for (int n = 0; n < 2; ++n)
#pragma unroll
            for (int reg = 0; reg < 4; ++reg) {
                int r = arow0 + wr * 64 + m * 16 + lgrp * 4 + reg;
                int c = brow0 + wc * 32 + n * 16 + lrow;
                P[(size_t)r * NPAD + c] = f2bf(acc[m][n][reg]);
            }
}

// ---------------- fused: split-K reduce + bias + tanh + FWHT + inv + norm ----
// One block per batch row. dot[c] = sum_j h[j]*H[c][j+1] = FWHT(g)[c] with
// g[0]=0, g[k]=h[k-1]  (Sylvester H symmetric; H[c][0]*g[0]=0 drops out).
__global__ __launch_bounds__(256) void k_fused(const unsigned short* __restrict__ partial,
                                               const float* __restrict__ bias,
                                               const float* __restrict__ epsp,
                                               const float* __restrict__ powp,
                                               float* __restrict__ out) {
    __shared__ float g[1024];
    __shared__ float wsum[4];
    const int r = blockIdx.x, t = threadIdx.x;
    const int n0 = t * 4;

    f32x4 v = {0.0f, 0.0f, 0.0f, 0.0f};
#pragma unroll
    for (int s = 0; s < SPLITK; ++s) {
        ushort4 p = *(const ushort4*)(partial + ((size_t)s * BATCH + r) * NPAD + n0);
        v[0] += bf2f(p.x); v[1] += bf2f(p.y); v[2] += bf2f(p.z); v[3] += bf2f(p.w);
    }
    float bb[4];
    if (t < 255) {
        float4 b4 = *(const float4*)(bias + n0);
        bb[0] = b4.x; bb[1] = b4.y; bb[2] = b4.z; bb[3] = b4.w;
    } else {
        bb[0] = bias[1020]; bb[1] = bias[1021]; bb[2] = bias[1022]; bb[3] = 0.0f;
    }
    if (t == 0) g[0] = 0.0f;
#pragma unroll
    for (int j = 0; j < 4; ++j) {
        int n = n0 + j;
        if (n < LOUT) g[n + 1] = tanhf(v[j] + bb[j]);
    }
    __syncthreads();

    // FWHT: 10 stages, 512 butterflies/stage, 2 per thread
#pragma unroll 1
    for (int s = 0; s < 10; ++s) {
        int st = 1 << s;
#pragma unroll
        for (int pp = 0; pp < 2; ++pp) {
            int p = t + pp * 256;
            int idx = ((p >> s) << (s + 1)) | (p & (st - 1));
            float a = g[idx], c = g[idx + st];
            g[idx] = a + c;
            g[idx + st] = a - c;
        }
        __syncthreads();
    }

    const float eps = *epsp, pw = *powp;
    float iv[4];
    float ss = 0.0f;
#pragma unroll
    for (int j = 0; j < 4; ++j) {
        int c = n0 + j;
        float d = fmaxf(1023.0f - g[c], eps);
        float q = (pw == 1.0f) ? (1.0f / d) : powf(d, -pw);
        if (c >= NCLS) q = 0.0f;
        iv[j] = q;
        ss += q;
    }
#pragma unroll
    for (int m = 32; m; m >>= 1) ss += __shfl_xor(ss, m, 64);
    if ((t & 63) == 0) wsum[t >> 6] = ss;
    __syncthreads();
    float sc = 1.0f / (wsum[0] + wsum[1] + wsum[2] + wsum[3]);

    if (n0 < NCLS) {  // NCLS = 1000 = 4*250: threads 0..249 store full float4
        float4 o;
        o.x = iv[0] * sc; o.y = iv[1] * sc; o.z = iv[2] * sc; o.w = iv[3] * sc;
        *(float4*)(out + (size_t)r * NCLS + n0) = o;
    }
}

extern "C" void kernel_launch(void* const* d_in, const int* in_sizes, int n_in,
                              void* d_out, int out_size, void* d_ws, size_t ws_size,
                              hipStream_t stream) {
    const float* x = (const float*)d_in[0];       // (512, 4096)
    const float* W = (const float*)d_in[1];       // (1023, 4096)
    const float* b = (const float*)d_in[2];       // (1023,)
    // d_in[3] = labels: NOT needed (Hadamard structure -> FWHT)
    const float* epsp = (const float*)d_in[4];
    const float* powp = (const float*)d_in[5];
    float* out = (float*)d_out;                   // (512, 1000)

    unsigned char* ws = (unsigned char*)d_ws;
    unsigned short* partial = (unsigned short*)ws;  // 8 MB (8 x 512 x 1024 bf16)

    k_gemm<<<256, 512, 0, stream>>>(x, W, partial);
    k_fused<<<512, 256, 0, stream>>>(partial, b, epsp, powp, out);
}

// Round 10
// 26.340 us; speedup vs baseline: 1.9636x; 1.0275x over previous
//
#include <hip/hip_runtime.h>

// Problem constants
#define BATCH 512
#define INFEAT 4096
#define LOUT 1023   // code_length - 1
#define NCLS 1000
#define NPAD 1024
#define SPLITK 8

typedef __bf16 bf16x8 __attribute__((ext_vector_type(8)));
typedef float f32x4 __attribute__((ext_vector_type(4)));

__device__ __forceinline__ unsigned short f2bf(float a) {
    unsigned u = __builtin_bit_cast(unsigned, a);
    return (unsigned short)((u + 0x7fffu + ((u >> 16) & 1u)) >> 16);
}
__device__ __forceinline__ float bf2f(unsigned short u) {
    return __builtin_bit_cast(float, ((unsigned)u) << 16);
}
// pack 8 f32 -> 8 bf16 (v_cvt_pk_bf16_f32 pairs)
__device__ __forceinline__ uint4 pack8(float4 a, float4 b) {
    union { __bf16 h[8]; uint4 u; } r;
    r.h[0] = (__bf16)a.x; r.h[1] = (__bf16)a.y;
    r.h[2] = (__bf16)a.z; r.h[3] = (__bf16)a.w;
    r.h[4] = (__bf16)b.x; r.h[5] = (__bf16)b.y;
    r.h[6] = (__bf16)b.z; r.h[7] = (__bf16)b.w;
    return r.u;
}

// ---------------- GEMM: partial[s] = bf16(x) @ bf16(W)^T (split-K) ----------
// OCCUPANCY-FIRST design (R9 post-mortem: per-block stalls were never the
// fixable cost; 1-2 blocks/CU meant nothing could hide them — m114/m97 run
// 3+ co-resident blocks). BM=BN=64, BK=64, SK=8 -> grid 1024 = 4 blocks/CU
// co-resident (LDS 32KB, VGPR<=128 via launch_bounds(256,4)). Per-block
// schedule kept SIMPLE: one staged reg-set, loads 1 step ahead; stalls are
// hidden by the other 3 blocks, not by intra-block pipelining (5 schedule
// variants R5-R9 proved that lever dead at this size).
// LDS: row stride 128B, granule slot s^(row&7) (uniform 8 lanes/bank-group
// on both ds_write_b128 and ds_read_b128).
// Chunked XCD swizzle: 128 consecutive works = one sp slice per XCD (~3 MB
// f32 working set, L2-resident re-reads).
__global__ __launch_bounds__(256, 4) void k_gemm(
    const float* __restrict__ x, const float* __restrict__ W,
    unsigned short* __restrict__ partial) {
    __shared__ unsigned char lds[32768];      // 2 x (8KB A + 8KB B)
    const int bid = blockIdx.x;
    const int work = (bid & 7) * 128 + (bid >> 3);  // chunked XCD swizzle
    const int bn = work & 15, bm = (work >> 4) & 7, sp = work >> 7;
    const int tid = threadIdx.x;
    const int wave = tid >> 6, lane = tid & 63;
    const int lrow = lane & 15, lgrp = lane >> 4;
    const int wr = wave >> 1, wc = wave & 1;        // 2 x 2 wave grid
    const int arow0 = bm * 64, brow0 = bn * 64, chunk0 = sp * 8;

    // staging coords: granule (row, s) ; thread owns granules tid and 256+tid
    const int row0 = tid >> 3, jb0 = tid & 7;        // rows 0..31
    const int row1 = 32 + (tid >> 3), jb1 = tid & 7; // rows 32..63

    f32x4 acc[2][2] = {};
    float4 sa[4], sb[4];   // one staged set: A granules x2, B granules x2

    auto LOADR = [&](int t) {
        const size_t c0 = (size_t)(chunk0 + t) * 64;
        {
            const float4* q = (const float4*)(x + (size_t)(arow0 + row0) * INFEAT + c0 + jb0 * 8);
            sa[0] = q[0]; sa[1] = q[1];
        }
        {
            const float4* q = (const float4*)(x + (size_t)(arow0 + row1) * INFEAT + c0 + jb1 * 8);
            sa[2] = q[0]; sa[3] = q[1];
        }
        {
            int wrow = brow0 + row0;
            if (wrow < LOUT) {
                const float4* q = (const float4*)(W + (size_t)wrow * INFEAT + c0 + jb0 * 8);
                sb[0] = q[0]; sb[1] = q[1];
            } else {
                sb[0] = make_float4(0.f, 0.f, 0.f, 0.f);
                sb[1] = make_float4(0.f, 0.f, 0.f, 0.f);
            }
        }
        {
            int wrow = brow0 + row1;
            if (wrow < LOUT) {
                const float4* q = (const float4*)(W + (size_t)wrow * INFEAT + c0 + jb1 * 8);
                sb[2] = q[0]; sb[3] = q[1];
            } else {
                sb[2] = make_float4(0.f, 0.f, 0.f, 0.f);
                sb[3] = make_float4(0.f, 0.f, 0.f, 0.f);
            }
        }
    };

    auto WRITE = [&](int bsel) {
        unsigned char* lA = lds + bsel * 16384;
        unsigned char* lB = lA + 8192;
        *(uint4*)(lA + row0 * 128 + ((jb0 ^ (row0 & 7)) * 16)) = pack8(sa[0], sa[1]);
        *(uint4*)(lA + row1 * 128 + ((jb1 ^ (row1 & 7)) * 16)) = pack8(sa[2], sa[3]);
        *(uint4*)(lB + row0 * 128 + ((jb0 ^ (row0 & 7)) * 16)) = pack8(sb[0], sb[1]);
        *(uint4*)(lB + row1 * 128 + ((jb1 ^ (row1 & 7)) * 16)) = pack8(sb[2], sb[3]);
    };

    // --- prologue: stage chunk 0 into buf 0 ---
    LOADR(0);
    WRITE(0);
    LOADR(1);              // issue next-chunk loads early
    __syncthreads();

#pragma unroll 1
    for (int t = 0; t < 8; ++t) {
        const int cur = t & 1;
        const unsigned char* lA = lds + cur * 16384;
        const unsigned char* lB = lA + 8192;
        // frag reads of buf cur
        bf16x8 fa[2][2], fb[2][2];
#pragma unroll
        for (int ks = 0; ks < 2; ++ks) {
            int swz = ((ks * 4 + lgrp) ^ (lrow & 7)) * 16;
#pragma unroll
            for (int m = 0; m < 2; ++m)
                fa[ks][m] = *(const bf16x8*)(lA + (wr * 32 + m * 16 + lrow) * 128 + swz);
#pragma unroll
            for (int n = 0; n < 2; ++n)
                fb[ks][n] = *(const bf16x8*)(lB + (wc * 32 + n * 16 + lrow) * 128 + swz);
        }
        // MFMA cluster (other co-resident blocks hide our stalls)
        __builtin_amdgcn_s_setprio(1);
#pragma unroll
        for (int ks = 0; ks < 2; ++ks)
#pragma unroll
            for (int m = 0; m < 2; ++m)
#pragma unroll
                for (int n = 0; n < 2; ++n)
                    acc[m][n] = __builtin_amdgcn_mfma_f32_16x16x32_bf16(
                        fa[ks][m], fb[ks][n], acc[m][n], 0, 0, 0);
        __builtin_amdgcn_s_setprio(0);
        if (t + 1 < 8) {
            WRITE(cur ^ 1);            // waits the staged set's vmcnt
            if (t + 2 < 8) LOADR(t + 2);
        }
        asm volatile("s_waitcnt lgkmcnt(0)" ::: "memory");
        __builtin_amdgcn_s_barrier();
    }

    // --- epilogue: bf16 partials ---
    unsigned short* P = partial + (size_t)sp * (BATCH * NPAD);
#pragma unroll
    for (int m = 0; m < 2; ++m)
#pragma unroll
        for (int n = 0; n < 2; ++n)
#pragma unroll
            for (int reg = 0; reg < 4; ++reg) {
                int r = arow0 + wr * 32 + m * 16 + lgrp * 4 + reg;
                int c = brow0 + wc * 32 + n * 16 + lrow;
                P[(size_t)r * NPAD + c] = f2bf(acc[m][n][reg]);
            }
}

// ---------------- fused: split-K reduce + bias + tanh + FWHT + inv + norm ----
// One block per batch row. dot[c] = sum_j h[j]*H[c][j+1] = FWHT(g)[c] with
// g[0]=0, g[k]=h[k-1]  (Sylvester H symmetric; H[c][0]*g[0]=0 drops out).
__global__ __launch_bounds__(256) void k_fused(const unsigned short* __restrict__ partial,
                                               const float* __restrict__ bias,
                                               const float* __restrict__ epsp,
                                               const float* __restrict__ powp,
                                               float* __restrict__ out) {
    __shared__ float g[1024];
    __shared__ float wsum[4];
    const int r = blockIdx.x, t = threadIdx.x;
    const int n0 = t * 4;

    f32x4 v = {0.0f, 0.0f, 0.0f, 0.0f};
#pragma unroll
    for (int s = 0; s < SPLITK; ++s) {
        ushort4 p = *(const ushort4*)(partial + ((size_t)s * BATCH + r) * NPAD + n0);
        v[0] += bf2f(p.x); v[1] += bf2f(p.y); v[2] += bf2f(p.z); v[3] += bf2f(p.w);
    }
    float bb[4];
    if (t < 255) {
        float4 b4 = *(const float4*)(bias + n0);
        bb[0] = b4.x; bb[1] = b4.y; bb[2] = b4.z; bb[3] = b4.w;
    } else {
        bb[0] = bias[1020]; bb[1] = bias[1021]; bb[2] = bias[1022]; bb[3] = 0.0f;
    }
    if (t == 0) g[0] = 0.0f;
#pragma unroll
    for (int j = 0; j < 4; ++j) {
        int n = n0 + j;
        if (n < LOUT) g[n + 1] = tanhf(v[j] + bb[j]);
    }
    __syncthreads();

    // FWHT: 10 stages, 512 butterflies/stage, 2 per thread
#pragma unroll 1
    for (int s = 0; s < 10; ++s) {
        int st = 1 << s;
#pragma unroll
        for (int pp = 0; pp < 2; ++pp) {
            int p = t + pp * 256;
            int idx = ((p >> s) << (s + 1)) | (p & (st - 1));
            float a = g[idx], c = g[idx + st];
            g[idx] = a + c;
            g[idx + st] = a - c;
        }
        __syncthreads();
    }

    const float eps = *epsp, pw = *powp;
    float iv[4];
    float ss = 0.0f;
#pragma unroll
    for (int j = 0; j < 4; ++j) {
        int c = n0 + j;
        float d = fmaxf(1023.0f - g[c], eps);
        float q = (pw == 1.0f) ? (1.0f / d) : powf(d, -pw);
        if (c >= NCLS) q = 0.0f;
        iv[j] = q;
        ss += q;
    }
#pragma unroll
    for (int m = 32; m; m >>= 1) ss += __shfl_xor(ss, m, 64);
    if ((t & 63) == 0) wsum[t >> 6] = ss;
    __syncthreads();
    float sc = 1.0f / (wsum[0] + wsum[1] + wsum[2] + wsum[3]);

    if (n0 < NCLS) {  // NCLS = 1000 = 4*250: threads 0..249 store full float4
        float4 o;
        o.x = iv[0] * sc; o.y = iv[1] * sc; o.z = iv[2] * sc; o.w = iv[3] * sc;
        *(float4*)(out + (size_t)r * NCLS + n0) = o;
    }
}

extern "C" void kernel_launch(void* const* d_in, const int* in_sizes, int n_in,
                              void* d_out, int out_size, void* d_ws, size_t ws_size,
                              hipStream_t stream) {
    const float* x = (const float*)d_in[0];       // (512, 4096)
    const float* W = (const float*)d_in[1];       // (1023, 4096)
    const float* b = (const float*)d_in[2];       // (1023,)
    // d_in[3] = labels: NOT needed (Hadamard structure -> FWHT)
    const float* epsp = (const float*)d_in[4];
    const float* powp = (const float*)d_in[5];
    float* out = (float*)d_out;                   // (512, 1000)

    unsigned char* ws = (unsigned char*)d_ws;
    unsigned short* partial = (unsigned short*)ws;  // 8 MB (8 x 512 x 1024 bf16)

    k_gemm<<<1024, 256, 0, stream>>>(x, W, partial);
    k_fused<<<512, 256, 0, stream>>>(partial, b, epsp, powp, out);
}